// Round 3
// baseline (84.524 us; speedup 1.0000x reference)
//
#include <hip/hip_runtime.h>
#include <hip/hip_bf16.h>

// CTC loss, linear-domain forward recurrence with windowed rescaling.
// One wave (64 lanes) per batch item; lane s < 33 owns extended-label state s.
// Triple-buffered 8-row register prefetch (A/B/C rotation) for memory-level
// parallelism: while computing superblock j, loads for j+1 and j+2 are in flight.
__global__ __launch_bounds__(256) void ctc_loss_kernel(
    const float* __restrict__ y_pred,
    const int*   __restrict__ labels,
    const int*   __restrict__ input_length,
    const int*   __restrict__ label_length,
    float*       __restrict__ out,
    int Bn)
{
    constexpr int T = 256, C = 96, L = 16;
    constexpr int NB = T / 8;             // 32 superblocks of 8 rows
    constexpr int blank = C - 1;          // 95
    constexpr float EPS = 1e-7f;

    const int lane = threadIdx.x & 63;
    const int b = blockIdx.x * 4 + (threadIdx.x >> 6);
    if (b >= Bn) return;                  // wave-uniform

    const int il = input_length[b];
    const int ll = label_length[b];
    const int s  = lane;

    int  extc = blank;
    bool skip_ok = false;
    if (s < 33 && (s & 1)) {
        extc = labels[b * L + (s >> 1)];
        if (s >= 3) skip_ok = (extc != labels[b * L + (s >> 1) - 1]);
    }
    const bool valid = (s < 2 * ll + 1);  // false for s >= 33 too

    const float* colp = y_pred + (size_t)b * T * C + extc;  // lane's column, stride C

    float bufA[8], bufB[8], bufC[8];
    float a = 0.0f, logC = 0.0f;

    // 8 loads from one base: row stride 384 B, max imm offset 2688 B (13-bit ok).
#define LOADB(Z, j)                                                   \
    do { if ((j) < NB) {                                              \
        const float* bp_ = colp + (size_t)(8 * (j)) * C;              \
        Z[0] = bp_[0];     Z[1] = bp_[C];     Z[2] = bp_[2 * C];      \
        Z[3] = bp_[3 * C]; Z[4] = bp_[4 * C]; Z[5] = bp_[5 * C];      \
        Z[6] = bp_[6 * C]; Z[7] = bp_[7 * C];                         \
    } } while (0)

#define STEP(yv, t)                                                   \
    do {                                                              \
        float p1_ = __shfl_up(a, 1, 64); p1_ = (s >= 1) ? p1_ : 0.0f; \
        float p2_ = __shfl_up(a, 2, 64); p2_ = skip_ok ? p2_ : 0.0f;  \
        float nw_ = (a + p1_ + p2_) * ((yv) + EPS);                   \
        nw_ = valid ? nw_ : 0.0f;                                     \
        a = ((t) < il) ? nw_ : a;                                     \
    } while (0)

#define RESCALE()                                                     \
    do {                                                              \
        float m_ = a;                                                 \
        m_ = fmaxf(m_, __shfl_xor(m_, 32, 64));                       \
        m_ = fmaxf(m_, __shfl_xor(m_, 16, 64));                       \
        m_ = fmaxf(m_, __shfl_xor(m_,  8, 64));                       \
        m_ = fmaxf(m_, __shfl_xor(m_,  4, 64));                       \
        m_ = fmaxf(m_, __shfl_xor(m_,  2, 64));                       \
        m_ = fmaxf(m_, __shfl_xor(m_,  1, 64));                       \
        logC += __logf(m_);                                           \
        a *= __builtin_amdgcn_rcpf(m_);                               \
    } while (0)

#define PROCB(Z, tb)                                                  \
    do {                                                              \
        STEP(Z[0], (tb));     STEP(Z[1], (tb) + 1);                   \
        STEP(Z[2], (tb) + 2); STEP(Z[3], (tb) + 3); RESCALE();        \
        STEP(Z[4], (tb) + 4); STEP(Z[5], (tb) + 5);                   \
        STEP(Z[6], (tb) + 6); STEP(Z[7], (tb) + 7); RESCALE();        \
    } while (0)

    // Prologue: fill all three buffers (blocks 0,1,2).
    LOADB(bufA, 0); LOADB(bufB, 1); LOADB(bufC, 2);

    // Block 0 (t = 0..7): init from row 0, then 7 steps.
    a = ((s == 0) | ((s == 1) & (ll >= 1))) ? (bufA[0] + EPS) : 0.0f;
    STEP(bufA[1], 1); STEP(bufA[2], 2); STEP(bufA[3], 3); RESCALE();
    STEP(bufA[4], 4); STEP(bufA[5], 5); STEP(bufA[6], 6); STEP(bufA[7], 7); RESCALE();
    LOADB(bufA, 3);

    PROCB(bufB, 8);  LOADB(bufB, 4);
    PROCB(bufC, 16); LOADB(bufC, 5);

    // Main loop: invariant at top — bufA=block j, bufB=j+1, bufC=j+2.
    #pragma unroll 1
    for (int j = 3; j <= 27; j += 3) {
        PROCB(bufA, 8 * j);       LOADB(bufA, j + 3);
        PROCB(bufB, 8 * (j + 1)); LOADB(bufB, j + 4);
        PROCB(bufC, 8 * (j + 2)); LOADB(bufC, j + 5);
    }
    // Tail: blocks 30 (A), 31 (B).
    PROCB(bufA, 240);
    PROCB(bufB, 248);

    // loss = il*log(1+C*eps) - logC - log(a[2ll] + a[2ll-1])
    const int i_b = 2 * ll;
    const int i_l = (2 * ll - 1 > 0) ? (2 * ll - 1) : 0;
    const float ab = __shfl(a, i_b, 64);
    const float al = __shfl(a, i_l, 64);
    const float p  = (ll > 0) ? (ab + al) : ab;
    const float loss = (float)il * logf(1.0f + (float)C * EPS) - logC - __logf(p);
    if (lane == 0) out[b] = loss;

#undef LOADB
#undef STEP
#undef RESCALE
#undef PROCB
}

extern "C" void kernel_launch(void* const* d_in, const int* in_sizes, int n_in,
                              void* d_out, int out_size, void* d_ws, size_t ws_size,
                              hipStream_t stream) {
    const float* y_pred       = (const float*)d_in[0];
    const int*   labels       = (const int*)d_in[1];
    const int*   input_length = (const int*)d_in[2];
    const int*   label_length = (const int*)d_in[3];
    float*       out          = (float*)d_out;

    const int B = in_sizes[2];
    const int blocks = (B + 3) / 4;
    ctc_loss_kernel<<<blocks, 256, 0, stream>>>(y_pred, labels, input_length,
                                                label_length, out, B);
}

// Round 4
// 72.212 us; speedup vs baseline: 1.1705x; 1.1705x over previous
//
#include <hip/hip_runtime.h>
#include <hip/hip_bf16.h>

// CTC loss, linear-domain forward recurrence with windowed rescaling.
// One wave (64 lanes) per batch item; lane s < 33 owns extended-label state s.
// All cross-lane traffic via DPP (VALU pipe) — zero LDS/DS instructions in the
// hot loop. Memory structure identical to the best-measured (round 2) version:
// constant-trip-count loop the compiler fully unrolls and schedules.

__device__ __forceinline__ float dpp_shr1(float x) {  // lane l <- lane l-1, lane 0 <- 0
    int r = __builtin_amdgcn_update_dpp(0, __builtin_bit_cast(int, x),
                                        0x138 /*wave_shr:1*/, 0xF, 0xF, true);
    return __builtin_bit_cast(float, r);
}

__global__ __launch_bounds__(256) void ctc_loss_kernel(
    const float* __restrict__ y_pred,
    const int*   __restrict__ labels,
    const int*   __restrict__ input_length,
    const int*   __restrict__ label_length,
    float*       __restrict__ out,
    int Bn)
{
    constexpr int T = 256, C = 96, L = 16;
    constexpr int blank = C - 1;          // 95
    constexpr float EPS = 1e-7f;

    const int lane = threadIdx.x & 63;
    const int b = blockIdx.x * 4 + (threadIdx.x >> 6);
    if (b >= Bn) return;                  // wave-uniform

    const int il = input_length[b];
    const int ll = label_length[b];
    const int s  = lane;

    int  extc = blank;
    bool skip_ok = false;
    if (s < 33 && (s & 1)) {
        extc = labels[b * L + (s >> 1)];
        if (s >= 3) skip_ok = (extc != labels[b * L + (s >> 1) - 1]);
    }
    const bool valid = (s < 2 * ll + 1);  // false for s >= 33 too

    const float* colp = y_pred + (size_t)b * T * C + extc;  // lane's column, stride C

    // preload rows 0..3
    float z0 = colp[0];
    float z1 = colp[C];
    float z2 = colp[2 * C];
    float z3 = colp[3 * C];

    float a = 0.0f, logC = 0.0f;

    // One forward step. p1 zero-fill at lane 0 comes free from DPP bound_ctrl.
    // valid-mask is applied only at rescale (invalid lanes never feed lanes <= 32).
    auto step = [&](float yv, int t) {
        float p1 = dpp_shr1(a);
        float p2 = dpp_shr1(p1);
        p2 = skip_ok ? p2 : 0.0f;
        float nw = (a + p1 + p2) * yv;
        a = (t < il) ? nw : a;
    };

    // Wave-uniform max via DPP tree (values >= 0, zero-fill harmless), then
    // readlane 63 -> scalar scale.
#define DPPMAX(mv, ctrl)                                                      \
    do { int s_ = __builtin_amdgcn_update_dpp(0, __builtin_bit_cast(int, mv), \
                                              (ctrl), 0xF, 0xF, true);        \
         mv = fmaxf(mv, __builtin_bit_cast(float, s_)); } while (0)

    auto rescale = [&]() {
        a = valid ? a : 0.0f;             // clear upward contamination
        float m = a;
        DPPMAX(m, 0x111);                 // row_shr:1
        DPPMAX(m, 0x112);                 // row_shr:2
        DPPMAX(m, 0x114);                 // row_shr:4
        DPPMAX(m, 0x118);                 // row_shr:8
        DPPMAX(m, 0x142);                 // row_bcast:15
        DPPMAX(m, 0x143);                 // row_bcast:31  -> lane 63 = wave max
        m = __builtin_bit_cast(float,
                __builtin_amdgcn_readlane(__builtin_bit_cast(int, m), 63));
        logC += __logf(m);
        a *= __builtin_amdgcn_rcpf(m);
    };

    // t = 0 init (linear domain)
    a = ((s == 0) | ((s == 1) & (ll >= 1))) ? z0 : 0.0f;

    // Block 0: steps 1..3 with block-1 prefetch already issued.
    {
        const float* bp = colp + (size_t)4 * C;
        float n0 = bp[0], n1 = bp[C], n2 = bp[2 * C], n3 = bp[3 * C];
        step(z1, 1); step(z2, 2); step(z3, 3);
        rescale();
        z0 = n0; z1 = n1; z2 = n2; z3 = n3;
    }
    // Blocks 1..63: prefetch block jb+1, run 4 steps on block jb, rescale.
    for (int jb = 1; jb < 64; ++jb) {
        float n0 = 0.0f, n1 = 0.0f, n2 = 0.0f, n3 = 0.0f;
        if (jb < 63) {
            const float* bp = colp + (size_t)(4 * (jb + 1)) * C;
            n0 = bp[0]; n1 = bp[C]; n2 = bp[2 * C]; n3 = bp[3 * C];
        }
        const int tb = 4 * jb;
        step(z0, tb); step(z1, tb + 1); step(z2, tb + 2); step(z3, tb + 3);
        rescale();
        z0 = n0; z1 = n1; z2 = n2; z3 = n3;
    }

    // loss = il*log(1+C*eps) - logC - log(a[2ll] + a[2ll-1])
    const int i_b = 2 * ll;
    const int i_l = (2 * ll - 1 > 0) ? (2 * ll - 1) : 0;
    const float ab = __shfl(a, i_b, 64);
    const float al = __shfl(a, i_l, 64);
    const float p  = (ll > 0) ? (ab + al) : ab;
    const float loss = (float)il * logf(1.0f + (float)C * EPS) - logC - __logf(p);
    if (lane == 0) out[b] = loss;
#undef DPPMAX
}

extern "C" void kernel_launch(void* const* d_in, const int* in_sizes, int n_in,
                              void* d_out, int out_size, void* d_ws, size_t ws_size,
                              hipStream_t stream) {
    const float* y_pred       = (const float*)d_in[0];
    const int*   labels       = (const int*)d_in[1];
    const int*   input_length = (const int*)d_in[2];
    const int*   label_length = (const int*)d_in[3];
    float*       out          = (float*)d_out;

    const int B = in_sizes[2];
    const int blocks = (B + 3) / 4;
    ctc_loss_kernel<<<blocks, 256, 0, stream>>>(y_pred, labels, input_length,
                                                label_length, out, B);
}